// Round 7
// baseline (443.198 us; speedup 1.0000x reference)
//
#include <hip/hip_runtime.h>

#define N_N 100000
#define N_E 1600000
#define N_G 5000
#define HID 256
#define IND 14

#define NB 391        // buckets: dst>>8, 256 nodes each (391*256 = 100096)
#define CH 4096       // edges per binning block
#define NBLK 391      // ceil(N_E/CH)

typedef __bf16 bf16x8 __attribute__((ext_vector_type(8)));
typedef float f32x4 __attribute__((ext_vector_type(4)));
typedef unsigned short u16;
typedef unsigned int u32;

// ---- workspace layout (units of 4 bytes) ----
constexpr size_t OFF_GCNT  = 0;          // float[5120]
constexpr size_t OFF_OUTS  = 5120;       // float[5120]
constexpr size_t ZERO_END  = 10240;
constexpr size_t ZERO_BYTES = ZERO_END * 4;
constexpr size_t OFF_ROWP  = 10240;      // int[100096]
constexpr size_t OFF_DEG   = 110592;     // int[100096]
constexpr size_t OFF_BCNT  = 210944;     // int[NBLK*NB]
constexpr size_t OFF_TOT   = 363840;     // int[512]
constexpr size_t OFF_BBASE = 364352;     // int[NB+1]
constexpr size_t OFF_EBUF  = 364800;     // u32[N_E]
constexpr size_t OFF_CSRC  = 1964800;    // int[N_E]
constexpr size_t OFF_H1B   = 3564800;    // bf16[N*256]
constexpr size_t OFF_MEAN1B= 16364800;   // bf16[N*256]
constexpr size_t OFF_WCAT  = 29164800;   // bf16[256*512]
constexpr size_t OFF_XP    = 29230336;   // float[N*16]
// end = 30830336 floats = ~123 MB

__device__ __forceinline__ u16 f2b(float f) {
    u32 u = __float_as_uint(f);
    u32 r = u + 0x7FFFu + ((u >> 16) & 1u);
    return (u16)(r >> 16);
}

#define ADD8(acc, v) do { \
    acc[0] += __uint_as_float(v.x << 16); \
    acc[1] += __uint_as_float(v.x & 0xFFFF0000u); \
    acc[2] += __uint_as_float(v.y << 16); \
    acc[3] += __uint_as_float(v.y & 0xFFFF0000u); \
    acc[4] += __uint_as_float(v.z << 16); \
    acc[5] += __uint_as_float(v.z & 0xFFFF0000u); \
    acc[6] += __uint_as_float(v.w << 16); \
    acc[7] += __uint_as_float(v.w & 0xFFFF0000u); \
} while (0)

// ---- phase A: per-block bucket histograms (no global atomics) ----
__global__ __launch_bounds__(256) void k_bcnt(const int* __restrict__ ei, int* __restrict__ bcnt) {
    __shared__ int hist[NB];
    int tid = threadIdx.x;
    for (int i = tid; i < NB; i += 256) hist[i] = 0;
    __syncthreads();
    int base = blockIdx.x * CH;
#pragma unroll
    for (int i = 0; i < 16; i++) {
        int e = base + i * 256 + tid;
        if (e < N_E) atomicAdd(&hist[ei[N_E + e] >> 8], 1);
    }
    __syncthreads();
    for (int i = tid; i < NB; i += 256) bcnt[(size_t)blockIdx.x * NB + i] = hist[i];
}

// ---- phase B1: per-bucket column scan (391 parallel blocks) ----
__global__ __launch_bounds__(512) void k_bscanA(int* __restrict__ bcnt, int* __restrict__ tot) {
    __shared__ int sc[512];
    int t = threadIdx.x;
    int b = blockIdx.x;
    int v = (t < NBLK) ? bcnt[(size_t)t * NB + b] : 0;
    sc[t] = v;
    __syncthreads();
    for (int off = 1; off < 512; off <<= 1) {
        int u = (t >= off) ? sc[t - off] : 0;
        __syncthreads();
        sc[t] += u;
        __syncthreads();
    }
    if (t < NBLK) bcnt[(size_t)t * NB + b] = sc[t] - v;   // exclusive within column
    if (t == 511) tot[b] = sc[511];
}

// ---- phase B2: scan bucket totals -> bbase ----
__global__ __launch_bounds__(512) void k_bscanB(const int* __restrict__ tot, int* __restrict__ bbase) {
    __shared__ int sc[512];
    int t = threadIdx.x;
    int v = (t < NB) ? tot[t] : 0;
    sc[t] = v;
    __syncthreads();
    for (int off = 1; off < 512; off <<= 1) {
        int u = (t >= off) ? sc[t - off] : 0;
        __syncthreads();
        sc[t] += u;
        __syncthreads();
    }
    if (t < NB) bbase[t] = sc[t] - v;
    if (t == NB - 1) bbase[NB] = sc[t];
}

// ---- phase C: bin edges into ebuf ----
__global__ __launch_bounds__(256) void k_bfill(const int* __restrict__ ei, const int* __restrict__ bcnt,
                                               const int* __restrict__ bbase, u32* __restrict__ ebuf) {
    __shared__ int cur[NB];
    int tid = threadIdx.x;
    for (int i = tid; i < NB; i += 256)
        cur[i] = bcnt[(size_t)blockIdx.x * NB + i] + bbase[i];
    __syncthreads();
    int base = blockIdx.x * CH;
#pragma unroll
    for (int i = 0; i < 16; i++) {
        int e = base + i * 256 + tid;
        if (e < N_E) {
            int d = ei[N_E + e];
            int s = ei[e];
            int p = atomicAdd(&cur[d >> 8], 1);
            ebuf[p] = (u32)s | ((u32)(d & 255) << 17);
        }
    }
}

// ---- phase D: per-bucket counting sort -> csrc, deg, rowp ----
__global__ __launch_bounds__(256) void k_sort(const u32* __restrict__ ebuf, const int* __restrict__ bbase,
                                              int* __restrict__ csrc, int* __restrict__ deg,
                                              int* __restrict__ rowp) {
    __shared__ int degL[256];
    __shared__ int sc[256];
    __shared__ int curL[256];
    int t = threadIdx.x;
    int b = blockIdx.x;
    int bs = bbase[b], be = bbase[b + 1];
    degL[t] = 0;
    __syncthreads();
    for (int e = bs + t; e < be; e += 256)
        atomicAdd(&degL[ebuf[e] >> 17], 1);
    __syncthreads();
    int myDeg = degL[t];
    sc[t] = myDeg;
    __syncthreads();
    for (int off = 1; off < 256; off <<= 1) {
        int v = (t >= off) ? sc[t - off] : 0;
        __syncthreads();
        sc[t] += v;
        __syncthreads();
    }
    int excl = sc[t] - myDeg;
    int node = (b << 8) + t;
    if (node < N_N) {
        deg[node] = myDeg;
        rowp[node] = bs + excl;
    }
    curL[t] = bs + excl;
    __syncthreads();
    for (int e = bs + t; e < be; e += 256) {
        u32 w = ebuf[e];
        int p = atomicAdd(&curL[w >> 17], 1);
        csrc[p] = (int)(w & 0x1FFFFu);
    }
}

// ---- pack x||pos into xp[N][16] fp32; fold gcnt count in ----
__global__ __launch_bounds__(256) void k_pack(const float* __restrict__ x, const float* __restrict__ pos,
                                              const int* __restrict__ batch,
                                              float* __restrict__ xp, float* __restrict__ gcnt) {
    int idx = blockIdx.x * 256 + threadIdx.x;   // N*16
    int n = idx >> 4, f = idx & 15;
    float v = 0.f;
    if (f < 11) v = x[n * 11 + f];
    else if (f < 14) v = pos[n * 3 + (f - 11)];
    xp[idx] = v;
    if (f == 0) atomicAdd(&gcnt[batch[n]], 1.0f);
}

// ---- W2 pre-transpose+concat into bf16 Wcat[n][k] ----
__global__ __launch_bounds__(256) void k_wcat(const float* __restrict__ W2l, const float* __restrict__ W2r,
                                              u16* __restrict__ wcat) {
    int idx = blockIdx.x * 256 + threadIdx.x;   // 256*512
    int n = idx >> 9, k = idx & 511;
    float v = (k < 256) ? W2l[k * HID + n] : W2r[(k - 256) * HID + n];
    wcat[(size_t)n * 512 + k] = f2b(v);
}

// ---- layer 1: wave-parallel CSR mean-agg + dual matmul + relu -> bf16 ----
__global__ __launch_bounds__(256) void k_layer1(const float* __restrict__ xp,
                                                const int* __restrict__ rowp, const int* __restrict__ deg,
                                                const int* __restrict__ csrc,
                                                const float* __restrict__ W1l, const float* __restrict__ b1,
                                                const float* __restrict__ W1r, u16* __restrict__ h1b) {
    __shared__ float ms[16][16];
    __shared__ float hs[16][16];
    int tid = threadIdx.x;
    int wave = tid >> 6, lane = tid & 63;
    int eg = lane >> 2, c = lane & 3;
    const float4* xp4 = (const float4*)xp;
#pragma unroll
    for (int nn = 0; nn < 4; nn++) {
        int s = wave * 4 + nn;
        int node = blockIdx.x * 16 + s;
        int st = rowp[node], dg = deg[node];
        float4 a = make_float4(0.f, 0.f, 0.f, 0.f);
        for (int e = st + eg; e < st + dg; e += 16) {
            int nb = csrc[e];
            float4 v = xp4[(size_t)nb * 4 + c];
            a.x += v.x; a.y += v.y; a.z += v.z; a.w += v.w;
        }
#pragma unroll
        for (int off = 32; off >= 4; off >>= 1) {
            a.x += __shfl_down(a.x, off);
            a.y += __shfl_down(a.y, off);
            a.z += __shfl_down(a.z, off);
            a.w += __shfl_down(a.w, off);
        }
        if (lane < 4) {
            float inv = 1.f / (float)max(dg, 1);
            ms[s][c * 4 + 0] = a.x * inv;
            ms[s][c * 4 + 1] = a.y * inv;
            ms[s][c * 4 + 2] = a.z * inv;
            ms[s][c * 4 + 3] = a.w * inv;
        } else if (lane < 8) {
            int cc = lane - 4;
            float4 v = xp4[(size_t)node * 4 + cc];
            hs[s][cc * 4 + 0] = v.x;
            hs[s][cc * 4 + 1] = v.y;
            hs[s][cc * 4 + 2] = v.z;
            hs[s][cc * 4 + 3] = v.w;
        }
    }
    __syncthreads();
    int j = tid;
    float bj = b1[j];
    float acc[16];
#pragma unroll
    for (int ss = 0; ss < 16; ss++) acc[ss] = bj;
#pragma unroll
    for (int k = 0; k < IND; k++) {
        float wl = W1l[k * HID + j];
        float wr = W1r[k * HID + j];
#pragma unroll
        for (int ss = 0; ss < 16; ss++)
            acc[ss] = fmaf(ms[ss][k], wl, fmaf(hs[ss][k], wr, acc[ss]));
    }
    int base = blockIdx.x * 16;
#pragma unroll
    for (int ss = 0; ss < 16; ss++)
        h1b[(size_t)(base + ss) * HID + j] = f2b(fmaxf(acc[ss], 0.f));
}

// ---- layer-2 mean aggregation: 1 wave/node, 8 rows in flight (4 per half-wave) ----
__global__ __launch_bounds__(256) void k_agg(const u16* __restrict__ h1b, const int* __restrict__ rowp,
                                             const int* __restrict__ deg, const int* __restrict__ csrc,
                                             u16* __restrict__ mean1b) {
    int tid = threadIdx.x;
    int node = blockIdx.x * 4 + (tid >> 6);
    int lane = tid & 63;
    int half = lane >> 5, l32 = lane & 31;
    int st = rowp[node], dg = deg[node];
    int end = st + dg;
    const size_t roff = (size_t)l32 * 8;
    float accA[8] = {}, accB[8] = {};
    int e = st;
    for (; e + 8 <= end; e += 8) {
        int b0 = e + half * 4;
        int i0 = csrc[b0 + 0];
        int i1 = csrc[b0 + 1];
        int i2 = csrc[b0 + 2];
        int i3 = csrc[b0 + 3];
        uint4 v0 = *(const uint4*)(h1b + (size_t)i0 * HID + roff);
        uint4 v1 = *(const uint4*)(h1b + (size_t)i1 * HID + roff);
        uint4 v2 = *(const uint4*)(h1b + (size_t)i2 * HID + roff);
        uint4 v3 = *(const uint4*)(h1b + (size_t)i3 * HID + roff);
        ADD8(accA, v0);
        ADD8(accB, v1);
        ADD8(accA, v2);
        ADD8(accB, v3);
    }
    for (int t = e + half; t < end; t += 2) {
        int nb = csrc[t];
        uint4 v = *(const uint4*)(h1b + (size_t)nb * HID + roff);
        ADD8(accA, v);
    }
    float acc[8];
#pragma unroll
    for (int j = 0; j < 8; j++) acc[j] = accA[j] + accB[j];
#pragma unroll
    for (int j = 0; j < 8; j++) acc[j] += __shfl_down(acc[j], 32);
    if (lane < 32) {
        float inv = 1.f / (float)max(dg, 1);
        uint4 o;
        o.x = (u32)f2b(acc[0] * inv) | ((u32)f2b(acc[1] * inv) << 16);
        o.y = (u32)f2b(acc[2] * inv) | ((u32)f2b(acc[3] * inv) << 16);
        o.z = (u32)f2b(acc[4] * inv) | ((u32)f2b(acc[5] * inv) << 16);
        o.w = (u32)f2b(acc[6] * inv) | ((u32)f2b(acc[7] * inv) << 16);
        *(uint4*)(mean1b + (size_t)node * HID + roff) = o;
    }
}

// ---- layer 2: bf16 MFMA GEMM + fused relu + Wout-dot + pool atomic ----
__global__ __launch_bounds__(256, 2) void k_layer2(const u16* __restrict__ mean1b, const u16* __restrict__ h1b,
                                                   const u16* __restrict__ wcat, const float* __restrict__ b2,
                                                   const int* __restrict__ batch, const float* __restrict__ Wout,
                                                   float* __restrict__ outsum) {
    __shared__ u16 As[128][40];
    __shared__ u16 Bs[256][40];
    int tid = threadIdx.x;
    int wave = tid >> 6, lane = tid & 63;
    int quad = lane >> 4, m16 = lane & 15;
    int bm = blockIdx.x;
    f32x4 acc[2][16] = {};
    for (int kt = 0; kt < 16; kt++) {
        const u16* Asrc = (kt < 8) ? mean1b : h1b;
        int kk = (kt & 7) * 32;
        __syncthreads();
#pragma unroll
        for (int i = 0; i < 2; i++) {
            int c = tid + 256 * i;
            int r = c >> 2, kc = c & 3;
            int grow = bm * 128 + r;
            uint4 v = make_uint4(0, 0, 0, 0);
            if (grow < N_N) v = *(const uint4*)(Asrc + (size_t)grow * HID + kk + kc * 8);
            *(uint4*)&As[r][kc * 8] = v;
        }
#pragma unroll
        for (int i = 0; i < 4; i++) {
            int c = tid + 256 * i;
            int n = c >> 2, kc = c & 3;
            uint4 v = *(const uint4*)(wcat + (size_t)n * 512 + kt * 32 + kc * 8);
            *(uint4*)&Bs[n][kc * 8] = v;
        }
        __syncthreads();
        bf16x8 afrag[2];
#pragma unroll
        for (int t = 0; t < 2; t++)
            afrag[t] = *(const bf16x8*)&As[wave * 32 + t * 16 + m16][quad * 8];
#pragma unroll
        for (int u = 0; u < 16; u++) {
            bf16x8 bfrag = *(const bf16x8*)&Bs[u * 16 + m16][quad * 8];
            acc[0][u] = __builtin_amdgcn_mfma_f32_16x16x32_bf16(afrag[0], bfrag, acc[0][u], 0, 0, 0);
            acc[1][u] = __builtin_amdgcn_mfma_f32_16x16x32_bf16(afrag[1], bfrag, acc[1][u], 0, 0, 0);
        }
    }
    float wo[16], bb[16];
#pragma unroll
    for (int u = 0; u < 16; u++) { int col = u * 16 + m16; wo[u] = Wout[col]; bb[u] = b2[col]; }
#pragma unroll
    for (int t = 0; t < 2; t++) {
#pragma unroll
        for (int i = 0; i < 4; i++) {
            float p = 0.f;
#pragma unroll
            for (int u = 0; u < 16; u++)
                p = fmaf(fmaxf(acc[t][u][i] + bb[u], 0.f), wo[u], p);
#pragma unroll
            for (int off = 8; off > 0; off >>= 1) p += __shfl_down(p, off, 16);
            int row = bm * 128 + wave * 32 + t * 16 + quad * 4 + i;
            if (m16 == 0 && row < N_N) atomicAdd(&outsum[batch[row]], p);
        }
    }
}

// ---- output head ----
__global__ __launch_bounds__(256) void k_out(const float* __restrict__ outsum, const float* __restrict__ gcnt,
                                             const float* __restrict__ bout, float* __restrict__ out) {
    int g = blockIdx.x * 256 + threadIdx.x;
    if (g < N_G) out[g] = outsum[g] / fmaxf(gcnt[g], 1.f) + bout[0];
}

extern "C" void kernel_launch(void* const* d_in, const int* in_sizes, int n_in,
                              void* d_out, int out_size, void* d_ws, size_t ws_size,
                              hipStream_t stream) {
    const float* x    = (const float*)d_in[0];
    const float* pos  = (const float*)d_in[1];
    const int*   ei   = (const int*)d_in[2];
    const int*   batch= (const int*)d_in[3];
    const float* W1l  = (const float*)d_in[4];
    const float* b1   = (const float*)d_in[5];
    const float* W1r  = (const float*)d_in[6];
    const float* W2l  = (const float*)d_in[7];
    const float* b2   = (const float*)d_in[8];
    const float* W2r  = (const float*)d_in[9];
    const float* Wout = (const float*)d_in[10];
    const float* bout = (const float*)d_in[11];
    float* out = (float*)d_out;
    float* ws  = (float*)d_ws;

    float* gcnt  = ws + OFF_GCNT;
    float* outs  = ws + OFF_OUTS;
    int*   rowp  = (int*)(ws + OFF_ROWP);
    int*   deg   = (int*)(ws + OFF_DEG);
    int*   bcnt  = (int*)(ws + OFF_BCNT);
    int*   tot   = (int*)(ws + OFF_TOT);
    int*   bbase = (int*)(ws + OFF_BBASE);
    u32*   ebuf  = (u32*)(ws + OFF_EBUF);
    int*   csrc  = (int*)(ws + OFF_CSRC);
    u16*   h1b   = (u16*)(ws + OFF_H1B);
    u16*   mean1b= (u16*)(ws + OFF_MEAN1B);
    u16*   wcat  = (u16*)(ws + OFF_WCAT);
    float* xp    = ws + OFF_XP;

    hipMemsetAsync(d_ws, 0, ZERO_BYTES, stream);
    k_bcnt  <<<NBLK, 256, 0, stream>>>(ei, bcnt);
    k_bscanA<<<NB, 512, 0, stream>>>(bcnt, tot);
    k_bscanB<<<1, 512, 0, stream>>>(tot, bbase);
    k_bfill <<<NBLK, 256, 0, stream>>>(ei, bcnt, bbase, ebuf);
    k_sort  <<<NB, 256, 0, stream>>>(ebuf, bbase, csrc, deg, rowp);
    k_pack  <<<(N_N * 16) / 256, 256, 0, stream>>>(x, pos, batch, xp, gcnt);
    k_wcat  <<<512, 256, 0, stream>>>(W2l, W2r, wcat);
    k_layer1<<<N_N / 16, 256, 0, stream>>>(xp, rowp, deg, csrc, W1l, b1, W1r, h1b);
    k_agg   <<<N_N / 4, 256, 0, stream>>>(h1b, rowp, deg, csrc, mean1b);
    k_layer2<<<(N_N + 127) / 128, 256, 0, stream>>>(mean1b, h1b, wcat, b2, batch, Wout, outs);
    k_out   <<<(N_G + 255) / 256, 256, 0, stream>>>(outs, gcnt, bout, out);
}

// Round 8
// 420.886 us; speedup vs baseline: 1.0530x; 1.0530x over previous
//
#include <hip/hip_runtime.h>

#define N_N 100000
#define N_E 1600000
#define N_G 5000
#define HID 256
#define IND 14

#define NB 391        // buckets: dst>>8, 256 nodes each (391*256 = 100096)
#define CH 8192       // edges per binning block
#define NBLK 196      // ceil(N_E/CH)

typedef __bf16 bf16x8 __attribute__((ext_vector_type(8)));
typedef float f32x4 __attribute__((ext_vector_type(4)));
typedef unsigned short u16;
typedef unsigned int u32;

// ---- workspace layout (units of 4 bytes) ----
constexpr size_t OFF_GCNT  = 0;          // float[5120]
constexpr size_t OFF_OUTS  = 5120;       // float[5120]
constexpr size_t ZERO_END  = 10240;
constexpr size_t ZERO_BYTES = ZERO_END * 4;
constexpr size_t OFF_ROWP  = 10240;      // int[100096]
constexpr size_t OFF_DEG   = 110592;     // int[100096]
constexpr size_t OFF_BCNT  = 210944;     // int[NBLK*NB] (76636)
constexpr size_t OFF_TOT   = 363840;     // int[512]
constexpr size_t OFF_BBASE = 364352;     // int[NB+1]
constexpr size_t OFF_EBUF  = 364800;     // u32[N_E]
constexpr size_t OFF_CSRC  = 1964800;    // int[N_E]
constexpr size_t OFF_H1B   = 3564800;    // bf16[N*256]
constexpr size_t OFF_MEAN1B= 16364800;   // bf16[N*256]
constexpr size_t OFF_WCAT  = 29164800;   // bf16[256*512]
constexpr size_t OFF_XP    = 29230336;   // float[N*16]
// end = 30830336 floats = ~123 MB

__device__ __forceinline__ u16 f2b(float f) {
    u32 u = __float_as_uint(f);
    u32 r = u + 0x7FFFu + ((u >> 16) & 1u);
    return (u16)(r >> 16);
}

#define ADD8(acc, v) do { \
    acc[0] += __uint_as_float(v.x << 16); \
    acc[1] += __uint_as_float(v.x & 0xFFFF0000u); \
    acc[2] += __uint_as_float(v.y << 16); \
    acc[3] += __uint_as_float(v.y & 0xFFFF0000u); \
    acc[4] += __uint_as_float(v.z << 16); \
    acc[5] += __uint_as_float(v.z & 0xFFFF0000u); \
    acc[6] += __uint_as_float(v.w << 16); \
    acc[7] += __uint_as_float(v.w & 0xFFFF0000u); \
} while (0)

// ---- phase A: per-block bucket histograms (no global atomics) ----
__global__ __launch_bounds__(256) void k_bcnt(const int* __restrict__ ei, int* __restrict__ bcnt) {
    __shared__ int hist[NB];
    int tid = threadIdx.x;
    for (int i = tid; i < NB; i += 256) hist[i] = 0;
    __syncthreads();
    int base = blockIdx.x * CH;
#pragma unroll
    for (int i = 0; i < 32; i++) {
        int e = base + i * 256 + tid;
        if (e < N_E) atomicAdd(&hist[ei[N_E + e] >> 8], 1);
    }
    __syncthreads();
    for (int i = tid; i < NB; i += 256) bcnt[(size_t)blockIdx.x * NB + i] = hist[i];
}

// ---- phase B1: per-bucket column scan (391 parallel blocks) ----
__global__ __launch_bounds__(512) void k_bscanA(int* __restrict__ bcnt, int* __restrict__ tot) {
    __shared__ int sc[512];
    int t = threadIdx.x;
    int b = blockIdx.x;
    int v = (t < NBLK) ? bcnt[(size_t)t * NB + b] : 0;
    sc[t] = v;
    __syncthreads();
    for (int off = 1; off < 512; off <<= 1) {
        int u = (t >= off) ? sc[t - off] : 0;
        __syncthreads();
        sc[t] += u;
        __syncthreads();
    }
    if (t < NBLK) bcnt[(size_t)t * NB + b] = sc[t] - v;   // exclusive within column
    if (t == 511) tot[b] = sc[511];
}

// ---- phase B2: scan bucket totals -> bbase ----
__global__ __launch_bounds__(512) void k_bscanB(const int* __restrict__ tot, int* __restrict__ bbase) {
    __shared__ int sc[512];
    int t = threadIdx.x;
    int v = (t < NB) ? tot[t] : 0;
    sc[t] = v;
    __syncthreads();
    for (int off = 1; off < 512; off <<= 1) {
        int u = (t >= off) ? sc[t - off] : 0;
        __syncthreads();
        sc[t] += u;
        __syncthreads();
    }
    if (t < NB) bbase[t] = sc[t] - v;
    if (t == NB - 1) bbase[NB] = sc[t];
}

// ---- phase C: bin edges into ebuf ----
__global__ __launch_bounds__(256) void k_bfill(const int* __restrict__ ei, const int* __restrict__ bcnt,
                                               const int* __restrict__ bbase, u32* __restrict__ ebuf) {
    __shared__ int cur[NB];
    int tid = threadIdx.x;
    for (int i = tid; i < NB; i += 256)
        cur[i] = bcnt[(size_t)blockIdx.x * NB + i] + bbase[i];
    __syncthreads();
    int base = blockIdx.x * CH;
#pragma unroll
    for (int i = 0; i < 32; i++) {
        int e = base + i * 256 + tid;
        if (e < N_E) {
            int d = ei[N_E + e];
            int s = ei[e];
            int p = atomicAdd(&cur[d >> 8], 1);
            ebuf[p] = (u32)s | ((u32)(d & 255) << 17);
        }
    }
}

// ---- phase D: per-bucket counting sort -> csrc, deg, rowp ----
__global__ __launch_bounds__(256) void k_sort(const u32* __restrict__ ebuf, const int* __restrict__ bbase,
                                              int* __restrict__ csrc, int* __restrict__ deg,
                                              int* __restrict__ rowp) {
    __shared__ int degL[256];
    __shared__ int sc[256];
    __shared__ int curL[256];
    int t = threadIdx.x;
    int b = blockIdx.x;
    int bs = bbase[b], be = bbase[b + 1];
    degL[t] = 0;
    __syncthreads();
    for (int e = bs + t; e < be; e += 256)
        atomicAdd(&degL[ebuf[e] >> 17], 1);
    __syncthreads();
    int myDeg = degL[t];
    sc[t] = myDeg;
    __syncthreads();
    for (int off = 1; off < 256; off <<= 1) {
        int v = (t >= off) ? sc[t - off] : 0;
        __syncthreads();
        sc[t] += v;
        __syncthreads();
    }
    int excl = sc[t] - myDeg;
    int node = (b << 8) + t;
    if (node < N_N) {
        deg[node] = myDeg;
        rowp[node] = bs + excl;
    }
    curL[t] = bs + excl;
    __syncthreads();
    for (int e = bs + t; e < be; e += 256) {
        u32 w = ebuf[e];
        int p = atomicAdd(&curL[w >> 17], 1);
        csrc[p] = (int)(w & 0x1FFFFu);
    }
}

// ---- prep: pack x||pos into xp[N][16] + gcnt, and build bf16 Wcat[n][k] (merged) ----
#define PACK_N (N_N * 16)
#define WCAT_N (256 * 512)
__global__ __launch_bounds__(256) void k_prep(const float* __restrict__ x, const float* __restrict__ pos,
                                              const int* __restrict__ batch,
                                              const float* __restrict__ W2l, const float* __restrict__ W2r,
                                              float* __restrict__ xp, float* __restrict__ gcnt,
                                              u16* __restrict__ wcat) {
    int idx = blockIdx.x * 256 + threadIdx.x;
    if (idx < PACK_N) {
        int n = idx >> 4, f = idx & 15;
        float v = 0.f;
        if (f < 11) v = x[n * 11 + f];
        else if (f < 14) v = pos[n * 3 + (f - 11)];
        xp[idx] = v;
        if (f == 0) atomicAdd(&gcnt[batch[n]], 1.0f);
    } else {
        int i2 = idx - PACK_N;
        if (i2 < WCAT_N) {
            int n = i2 >> 9, k = i2 & 511;
            float v = (k < 256) ? W2l[k * HID + n] : W2r[(k - 256) * HID + n];
            wcat[(size_t)n * 512 + k] = f2b(v);
        }
    }
}

// ---- layer 1: wave-parallel CSR mean-agg + dual matmul + relu -> bf16 ----
__global__ __launch_bounds__(256) void k_layer1(const float* __restrict__ xp,
                                                const int* __restrict__ rowp, const int* __restrict__ deg,
                                                const int* __restrict__ csrc,
                                                const float* __restrict__ W1l, const float* __restrict__ b1,
                                                const float* __restrict__ W1r, u16* __restrict__ h1b) {
    __shared__ float ms[16][16];
    __shared__ float hs[16][16];
    int tid = threadIdx.x;
    int wave = tid >> 6, lane = tid & 63;
    int eg = lane >> 2, c = lane & 3;
    const float4* xp4 = (const float4*)xp;
#pragma unroll
    for (int nn = 0; nn < 4; nn++) {
        int s = wave * 4 + nn;
        int node = blockIdx.x * 16 + s;
        int st = rowp[node], dg = deg[node];
        float4 a = make_float4(0.f, 0.f, 0.f, 0.f);
        for (int e = st + eg; e < st + dg; e += 16) {
            int nb = csrc[e];
            float4 v = xp4[(size_t)nb * 4 + c];
            a.x += v.x; a.y += v.y; a.z += v.z; a.w += v.w;
        }
#pragma unroll
        for (int off = 32; off >= 4; off >>= 1) {
            a.x += __shfl_down(a.x, off);
            a.y += __shfl_down(a.y, off);
            a.z += __shfl_down(a.z, off);
            a.w += __shfl_down(a.w, off);
        }
        if (lane < 4) {
            float inv = 1.f / (float)max(dg, 1);
            ms[s][c * 4 + 0] = a.x * inv;
            ms[s][c * 4 + 1] = a.y * inv;
            ms[s][c * 4 + 2] = a.z * inv;
            ms[s][c * 4 + 3] = a.w * inv;
        } else if (lane < 8) {
            int cc = lane - 4;
            float4 v = xp4[(size_t)node * 4 + cc];
            hs[s][cc * 4 + 0] = v.x;
            hs[s][cc * 4 + 1] = v.y;
            hs[s][cc * 4 + 2] = v.z;
            hs[s][cc * 4 + 3] = v.w;
        }
    }
    __syncthreads();
    int j = tid;
    float bj = b1[j];
    float acc[16];
#pragma unroll
    for (int ss = 0; ss < 16; ss++) acc[ss] = bj;
#pragma unroll
    for (int k = 0; k < IND; k++) {
        float wl = W1l[k * HID + j];
        float wr = W1r[k * HID + j];
#pragma unroll
        for (int ss = 0; ss < 16; ss++)
            acc[ss] = fmaf(ms[ss][k], wl, fmaf(hs[ss][k], wr, acc[ss]));
    }
    int base = blockIdx.x * 16;
#pragma unroll
    for (int ss = 0; ss < 16; ss++)
        h1b[(size_t)(base + ss) * HID + j] = f2b(fmaxf(acc[ss], 0.f));
}

// ---- layer-2 mean aggregation: 1 wave/node, 4 rows in flight (R6 variant; at the
// scattered-gather fabric-BW wall ~3.9 TB/s — concurrency scaling falsified in R7) ----
__global__ __launch_bounds__(256) void k_agg(const u16* __restrict__ h1b, const int* __restrict__ rowp,
                                             const int* __restrict__ deg, const int* __restrict__ csrc,
                                             u16* __restrict__ mean1b) {
    int tid = threadIdx.x;
    int node = blockIdx.x * 4 + (tid >> 6);
    int lane = tid & 63;
    int half = lane >> 5, l32 = lane & 31;
    int st = rowp[node], dg = deg[node];
    int end = st + dg;
    const size_t roff = (size_t)l32 * 8;
    float accA[8] = {}, accB[8] = {};
    int e = st + half;
    for (; e + 2 < end; e += 4) {
        int nb1 = csrc[e];
        int nb2 = csrc[e + 2];
        uint4 v1 = *(const uint4*)(h1b + (size_t)nb1 * HID + roff);
        uint4 v2 = *(const uint4*)(h1b + (size_t)nb2 * HID + roff);
        ADD8(accA, v1);
        ADD8(accB, v2);
    }
    if (e < end) {
        int nb = csrc[e];
        uint4 v = *(const uint4*)(h1b + (size_t)nb * HID + roff);
        ADD8(accA, v);
    }
    float acc[8];
#pragma unroll
    for (int j = 0; j < 8; j++) acc[j] = accA[j] + accB[j];
#pragma unroll
    for (int j = 0; j < 8; j++) acc[j] += __shfl_down(acc[j], 32);
    if (lane < 32) {
        float inv = 1.f / (float)max(dg, 1);
        uint4 o;
        o.x = (u32)f2b(acc[0] * inv) | ((u32)f2b(acc[1] * inv) << 16);
        o.y = (u32)f2b(acc[2] * inv) | ((u32)f2b(acc[3] * inv) << 16);
        o.z = (u32)f2b(acc[4] * inv) | ((u32)f2b(acc[5] * inv) << 16);
        o.w = (u32)f2b(acc[6] * inv) | ((u32)f2b(acc[7] * inv) << 16);
        *(uint4*)(mean1b + (size_t)node * HID + roff) = o;
    }
}

// ---- layer 2: bf16 MFMA GEMM, A-frags loaded DIRECTLY from global (layout
// m=lane&15, k=quad*8+j == per-lane contiguous 16 B), register prefetch of next
// kt's A while MFMAs run. B staged in LDS per kt. Fused relu+Wout-dot+pool atomic. ----
__global__ __launch_bounds__(256, 2) void k_layer2(const u16* __restrict__ mean1b, const u16* __restrict__ h1b,
                                                   const u16* __restrict__ wcat, const float* __restrict__ b2,
                                                   const int* __restrict__ batch, const float* __restrict__ Wout,
                                                   float* __restrict__ outsum) {
    __shared__ u16 Bs[256][40];
    int tid = threadIdx.x;
    int wave = tid >> 6, lane = tid & 63;
    int quad = lane >> 4, m16 = lane & 15;
    int bm = blockIdx.x;
    // this lane's two A rows (m-tiles t=0,1); OOB rows read garbage inside d_ws and are
    // discarded in the epilogue (row < N_N guard)
    const size_t r0 = (size_t)(bm * 128 + wave * 32 + m16) * HID + quad * 8;
    const size_t r1 = r0 + 16 * HID;
    f32x4 acc[2][16] = {};
    uint4 a0 = *(const uint4*)(mean1b + r0);
    uint4 a1 = *(const uint4*)(mean1b + r1);
    for (int kt = 0; kt < 16; kt++) {
        __syncthreads();
#pragma unroll
        for (int i = 0; i < 4; i++) {
            int c = tid + 256 * i;
            int n = c >> 2, kc = c & 3;
            uint4 v = *(const uint4*)(wcat + (size_t)n * 512 + kt * 32 + kc * 8);
            *(uint4*)&Bs[n][kc * 8] = v;
        }
        __syncthreads();
        uint4 cur0 = a0, cur1 = a1;
        if (kt < 15) {
            int kg = (kt + 1) * 32;
            const u16* An = (kg < 256) ? (mean1b + kg) : (h1b + (kg - 256));
            a0 = *(const uint4*)(An + r0);
            a1 = *(const uint4*)(An + r1);
        }
        bf16x8 af0 = __builtin_bit_cast(bf16x8, cur0);
        bf16x8 af1 = __builtin_bit_cast(bf16x8, cur1);
#pragma unroll
        for (int u = 0; u < 16; u++) {
            bf16x8 bfrag = *(const bf16x8*)&Bs[u * 16 + m16][quad * 8];
            acc[0][u] = __builtin_amdgcn_mfma_f32_16x16x32_bf16(af0, bfrag, acc[0][u], 0, 0, 0);
            acc[1][u] = __builtin_amdgcn_mfma_f32_16x16x32_bf16(af1, bfrag, acc[1][u], 0, 0, 0);
        }
    }
    float wo[16], bb[16];
#pragma unroll
    for (int u = 0; u < 16; u++) { int col = u * 16 + m16; wo[u] = Wout[col]; bb[u] = b2[col]; }
#pragma unroll
    for (int t = 0; t < 2; t++) {
#pragma unroll
        for (int i = 0; i < 4; i++) {
            float p = 0.f;
#pragma unroll
            for (int u = 0; u < 16; u++)
                p = fmaf(fmaxf(acc[t][u][i] + bb[u], 0.f), wo[u], p);
#pragma unroll
            for (int off = 8; off > 0; off >>= 1) p += __shfl_down(p, off, 16);
            int row = bm * 128 + wave * 32 + t * 16 + quad * 4 + i;
            if (m16 == 0 && row < N_N) atomicAdd(&outsum[batch[row]], p);
        }
    }
}

// ---- output head ----
__global__ __launch_bounds__(256) void k_out(const float* __restrict__ outsum, const float* __restrict__ gcnt,
                                             const float* __restrict__ bout, float* __restrict__ out) {
    int g = blockIdx.x * 256 + threadIdx.x;
    if (g < N_G) out[g] = outsum[g] / fmaxf(gcnt[g], 1.f) + bout[0];
}

extern "C" void kernel_launch(void* const* d_in, const int* in_sizes, int n_in,
                              void* d_out, int out_size, void* d_ws, size_t ws_size,
                              hipStream_t stream) {
    const float* x    = (const float*)d_in[0];
    const float* pos  = (const float*)d_in[1];
    const int*   ei   = (const int*)d_in[2];
    const int*   batch= (const int*)d_in[3];
    const float* W1l  = (const float*)d_in[4];
    const float* b1   = (const float*)d_in[5];
    const float* W1r  = (const float*)d_in[6];
    const float* W2l  = (const float*)d_in[7];
    const float* b2   = (const float*)d_in[8];
    const float* W2r  = (const float*)d_in[9];
    const float* Wout = (const float*)d_in[10];
    const float* bout = (const float*)d_in[11];
    float* out = (float*)d_out;
    float* ws  = (float*)d_ws;

    float* gcnt  = ws + OFF_GCNT;
    float* outs  = ws + OFF_OUTS;
    int*   rowp  = (int*)(ws + OFF_ROWP);
    int*   deg   = (int*)(ws + OFF_DEG);
    int*   bcnt  = (int*)(ws + OFF_BCNT);
    int*   tot   = (int*)(ws + OFF_TOT);
    int*   bbase = (int*)(ws + OFF_BBASE);
    u32*   ebuf  = (u32*)(ws + OFF_EBUF);
    int*   csrc  = (int*)(ws + OFF_CSRC);
    u16*   h1b   = (u16*)(ws + OFF_H1B);
    u16*   mean1b= (u16*)(ws + OFF_MEAN1B);
    u16*   wcat  = (u16*)(ws + OFF_WCAT);
    float* xp    = ws + OFF_XP;

    hipMemsetAsync(d_ws, 0, ZERO_BYTES, stream);
    k_bcnt  <<<NBLK, 256, 0, stream>>>(ei, bcnt);
    k_bscanA<<<NB, 512, 0, stream>>>(bcnt, tot);
    k_bscanB<<<1, 512, 0, stream>>>(tot, bbase);
    k_bfill <<<NBLK, 256, 0, stream>>>(ei, bcnt, bbase, ebuf);
    k_sort  <<<NB, 256, 0, stream>>>(ebuf, bbase, csrc, deg, rowp);
    k_prep  <<<(PACK_N + WCAT_N + 255) / 256, 256, 0, stream>>>(x, pos, batch, W2l, W2r, xp, gcnt, wcat);
    k_layer1<<<N_N / 16, 256, 0, stream>>>(xp, rowp, deg, csrc, W1l, b1, W1r, h1b);
    k_agg   <<<N_N / 4, 256, 0, stream>>>(h1b, rowp, deg, csrc, mean1b);
    k_layer2<<<(N_N + 127) / 128, 256, 0, stream>>>(mean1b, h1b, wcat, b2, batch, Wout, outs);
    k_out   <<<(N_G + 255) / 256, 256, 0, stream>>>(outs, gcnt, bout, out);
}

// Round 9
// 410.702 us; speedup vs baseline: 1.0791x; 1.0248x over previous
//
#include <hip/hip_runtime.h>

#define N_N 100000
#define N_E 1600000
#define N_G 5000
#define HID 256
#define IND 14

#define NB 391        // buckets: dst>>8, 256 nodes each (391*256 = 100096)
#define CH 8192       // edges per binning block
#define NBLK 196      // ceil(N_E/CH)

typedef __bf16 bf16x8 __attribute__((ext_vector_type(8)));
typedef float f32x4 __attribute__((ext_vector_type(4)));
typedef unsigned short u16;
typedef unsigned int u32;

// ---- workspace layout (units of 4 bytes) ----
constexpr size_t OFF_GCNT  = 0;          // float[5120]
constexpr size_t OFF_OUTS  = 5120;       // float[5120]
constexpr size_t ZERO_END  = 10240;
constexpr size_t ZERO_BYTES = ZERO_END * 4;
constexpr size_t OFF_ROWP  = 10240;      // int[100096]
constexpr size_t OFF_DEG   = 110592;     // int[100096]
constexpr size_t OFF_BCNT  = 210944;     // int[NBLK*NB]
constexpr size_t OFF_TOT   = 363840;     // int[512]
constexpr size_t OFF_EBUF  = 364800;     // u32[N_E]
constexpr size_t OFF_CSRC  = 1964800;    // int[N_E]
constexpr size_t OFF_H1B   = 3564800;    // bf16[N*256]
constexpr size_t OFF_MEAN1B= 16364800;   // bf16[N*256]
constexpr size_t OFF_WCAT  = 29164800;   // bf16[256*512]
constexpr size_t OFF_XP    = 29230336;   // bf16[N*16]
// end ~ 30030336 floats = ~120 MB

__device__ __forceinline__ u16 f2b(float f) {
    u32 u = __float_as_uint(f);
    u32 r = u + 0x7FFFu + ((u >> 16) & 1u);
    return (u16)(r >> 16);
}

#define ADD8(acc, v) do { \
    acc[0] += __uint_as_float(v.x << 16); \
    acc[1] += __uint_as_float(v.x & 0xFFFF0000u); \
    acc[2] += __uint_as_float(v.y << 16); \
    acc[3] += __uint_as_float(v.y & 0xFFFF0000u); \
    acc[4] += __uint_as_float(v.z << 16); \
    acc[5] += __uint_as_float(v.z & 0xFFFF0000u); \
    acc[6] += __uint_as_float(v.w << 16); \
    acc[7] += __uint_as_float(v.w & 0xFFFF0000u); \
} while (0)

// ---- merged: bucket histograms (blocks 0..NBLK-1) + prep (pack xp bf16, gcnt, wcat) ----
#define PACK_N (N_N * 16)
#define WCAT_N (256 * 512)
#define PREP_BLKS ((PACK_N + WCAT_N) / 256)
__global__ __launch_bounds__(256) void k_bcnt_prep(const int* __restrict__ ei,
                                                   const float* __restrict__ x, const float* __restrict__ pos,
                                                   const int* __restrict__ batch,
                                                   const float* __restrict__ W2l, const float* __restrict__ W2r,
                                                   int* __restrict__ bcnt, u16* __restrict__ xpb,
                                                   float* __restrict__ gcnt, u16* __restrict__ wcat) {
    __shared__ int hist[NB];
    int tid = threadIdx.x;
    if (blockIdx.x < NBLK) {
        for (int i = tid; i < NB; i += 256) hist[i] = 0;
        __syncthreads();
        int base = blockIdx.x * CH;
#pragma unroll
        for (int i = 0; i < 32; i++) {
            int e = base + i * 256 + tid;
            if (e < N_E) atomicAdd(&hist[ei[N_E + e] >> 8], 1);
        }
        __syncthreads();
        for (int i = tid; i < NB; i += 256) bcnt[(size_t)blockIdx.x * NB + i] = hist[i];
    } else {
        int idx = (blockIdx.x - NBLK) * 256 + tid;
        if (idx < PACK_N) {
            int n = idx >> 4, f = idx & 15;
            float v = 0.f;
            if (f < 11) v = x[n * 11 + f];
            else if (f < 14) v = pos[n * 3 + (f - 11)];
            xpb[idx] = f2b(v);
            if (f == 0) atomicAdd(&gcnt[batch[n]], 1.0f);
        } else {
            int i2 = idx - PACK_N;
            int n = i2 >> 9, k = i2 & 511;
            float v = (k < 256) ? W2l[k * HID + n] : W2r[(k - 256) * HID + n];
            wcat[(size_t)n * 512 + k] = f2b(v);
        }
    }
}

// ---- per-bucket column scan (NB parallel blocks) ----
__global__ __launch_bounds__(512) void k_bscanA(int* __restrict__ bcnt, int* __restrict__ tot) {
    __shared__ int sc[512];
    int t = threadIdx.x;
    int b = blockIdx.x;
    int v = (t < NBLK) ? bcnt[(size_t)t * NB + b] : 0;
    sc[t] = v;
    __syncthreads();
    for (int off = 1; off < 512; off <<= 1) {
        int u = (t >= off) ? sc[t - off] : 0;
        __syncthreads();
        sc[t] += u;
        __syncthreads();
    }
    if (t < NBLK) bcnt[(size_t)t * NB + b] = sc[t] - v;   // exclusive within column
    if (t == 511) tot[b] = sc[511];
}

// ---- bin edges into ebuf; bucket bases computed locally from tot (no k_bscanB) ----
__global__ __launch_bounds__(512) void k_bfill(const int* __restrict__ ei, const int* __restrict__ bcnt,
                                               const int* __restrict__ tot, u32* __restrict__ ebuf) {
    __shared__ int cur[NB];
    __shared__ int sc[512];
    int t = threadIdx.x;
    int v = (t < NB) ? tot[t] : 0;
    sc[t] = v;
    __syncthreads();
    for (int off = 1; off < 512; off <<= 1) {
        int u = (t >= off) ? sc[t - off] : 0;
        __syncthreads();
        sc[t] += u;
        __syncthreads();
    }
    if (t < NB) cur[t] = bcnt[(size_t)blockIdx.x * NB + t] + (sc[t] - v);
    __syncthreads();
    int base = blockIdx.x * CH;
#pragma unroll
    for (int i = 0; i < 16; i++) {
        int e = base + i * 512 + t;
        if (e < N_E) {
            int d = ei[N_E + e];
            int s = ei[e];
            int p = atomicAdd(&cur[d >> 8], 1);
            ebuf[p] = (u32)s | ((u32)(d & 255) << 17);
        }
    }
}

// ---- per-bucket counting sort -> csrc, deg, rowp (bucket base via local reduce) ----
__global__ __launch_bounds__(256) void k_sort(const u32* __restrict__ ebuf, const int* __restrict__ tot,
                                              int* __restrict__ csrc, int* __restrict__ deg,
                                              int* __restrict__ rowp) {
    __shared__ int degL[256];
    __shared__ int sc[256];
    __shared__ int curL[256];
    __shared__ int red[256];
    int t = threadIdx.x;
    int b = blockIdx.x;
    int partial = 0;
    for (int i = t; i < b; i += 256) partial += tot[i];
    red[t] = partial;
    degL[t] = 0;
    __syncthreads();
    for (int off = 128; off > 0; off >>= 1) {
        if (t < off) red[t] += red[t + off];
        __syncthreads();
    }
    int bs = red[0];
    int be = bs + tot[b];
    for (int e = bs + t; e < be; e += 256)
        atomicAdd(&degL[ebuf[e] >> 17], 1);
    __syncthreads();
    int myDeg = degL[t];
    sc[t] = myDeg;
    __syncthreads();
    for (int off = 1; off < 256; off <<= 1) {
        int v = (t >= off) ? sc[t - off] : 0;
        __syncthreads();
        sc[t] += v;
        __syncthreads();
    }
    int excl = sc[t] - myDeg;
    int node = (b << 8) + t;
    if (node < N_N) {
        deg[node] = myDeg;
        rowp[node] = bs + excl;
    }
    curL[t] = bs + excl;
    __syncthreads();
    for (int e = bs + t; e < be; e += 256) {
        u32 w = ebuf[e];
        int p = atomicAdd(&curL[w >> 17], 1);
        csrc[p] = (int)(w & 0x1FFFFu);
    }
}

// ---- layer 1: wave-parallel CSR mean-agg on bf16 xp (32 edges in flight) + dual matmul + relu ----
__global__ __launch_bounds__(256) void k_layer1(const u16* __restrict__ xpb,
                                                const int* __restrict__ rowp, const int* __restrict__ deg,
                                                const int* __restrict__ csrc,
                                                const float* __restrict__ W1l, const float* __restrict__ b1,
                                                const float* __restrict__ W1r, u16* __restrict__ h1b) {
    __shared__ float ms[16][16];
    __shared__ float hs[16][16];
    int tid = threadIdx.x;
    int wave = tid >> 6, lane = tid & 63;
    int eg = lane >> 1, c = lane & 1;
#pragma unroll
    for (int nn = 0; nn < 4; nn++) {
        int s = wave * 4 + nn;
        int node = blockIdx.x * 16 + s;
        int st = rowp[node], dg = deg[node];
        float a[8] = {};
        for (int e = st + eg; e < st + dg; e += 32) {
            int nb = csrc[e];
            uint4 v = *(const uint4*)(xpb + (size_t)nb * 16 + c * 8);
            ADD8(a, v);
        }
#pragma unroll
        for (int off = 32; off >= 2; off >>= 1) {
#pragma unroll
            for (int j = 0; j < 8; j++) a[j] += __shfl_down(a[j], off);
        }
        if (lane < 2) {
            float inv = 1.f / (float)max(dg, 1);
#pragma unroll
            for (int j = 0; j < 8; j++) ms[s][c * 8 + j] = a[j] * inv;
        } else if (lane < 4) {
            int cc = lane - 2;
            uint4 v = *(const uint4*)(xpb + (size_t)node * 16 + cc * 8);
            float h[8] = {};
            ADD8(h, v);
#pragma unroll
            for (int j = 0; j < 8; j++) hs[s][cc * 8 + j] = h[j];
        }
    }
    __syncthreads();
    int j = tid;
    float bj = b1[j];
    float acc[16];
#pragma unroll
    for (int ss = 0; ss < 16; ss++) acc[ss] = bj;
#pragma unroll
    for (int k = 0; k < IND; k++) {
        float wl = W1l[k * HID + j];
        float wr = W1r[k * HID + j];
#pragma unroll
        for (int ss = 0; ss < 16; ss++)
            acc[ss] = fmaf(ms[ss][k], wl, fmaf(hs[ss][k], wr, acc[ss]));
    }
    int base = blockIdx.x * 16;
#pragma unroll
    for (int ss = 0; ss < 16; ss++)
        h1b[(size_t)(base + ss) * HID + j] = f2b(fmaxf(acc[ss], 0.f));
}

// ---- layer-2 mean aggregation: 1 wave/node, 4 rows in flight (at the scattered-gather
// service-rate wall ~3.9 TB/s L2-miss; concurrency scaling falsified in R7) ----
__global__ __launch_bounds__(256) void k_agg(const u16* __restrict__ h1b, const int* __restrict__ rowp,
                                             const int* __restrict__ deg, const int* __restrict__ csrc,
                                             u16* __restrict__ mean1b) {
    int tid = threadIdx.x;
    int node = blockIdx.x * 4 + (tid >> 6);
    int lane = tid & 63;
    int half = lane >> 5, l32 = lane & 31;
    int st = rowp[node], dg = deg[node];
    int end = st + dg;
    const size_t roff = (size_t)l32 * 8;
    float accA[8] = {}, accB[8] = {};
    int e = st + half;
    for (; e + 2 < end; e += 4) {
        int nb1 = csrc[e];
        int nb2 = csrc[e + 2];
        uint4 v1 = *(const uint4*)(h1b + (size_t)nb1 * HID + roff);
        uint4 v2 = *(const uint4*)(h1b + (size_t)nb2 * HID + roff);
        ADD8(accA, v1);
        ADD8(accB, v2);
    }
    if (e < end) {
        int nb = csrc[e];
        uint4 v = *(const uint4*)(h1b + (size_t)nb * HID + roff);
        ADD8(accA, v);
    }
    float acc[8];
#pragma unroll
    for (int j = 0; j < 8; j++) acc[j] = accA[j] + accB[j];
#pragma unroll
    for (int j = 0; j < 8; j++) acc[j] += __shfl_down(acc[j], 32);
    if (lane < 32) {
        float inv = 1.f / (float)max(dg, 1);
        uint4 o;
        o.x = (u32)f2b(acc[0] * inv) | ((u32)f2b(acc[1] * inv) << 16);
        o.y = (u32)f2b(acc[2] * inv) | ((u32)f2b(acc[3] * inv) << 16);
        o.z = (u32)f2b(acc[4] * inv) | ((u32)f2b(acc[5] * inv) << 16);
        o.w = (u32)f2b(acc[6] * inv) | ((u32)f2b(acc[7] * inv) << 16);
        *(uint4*)(mean1b + (size_t)node * HID + roff) = o;
    }
}

// ---- layer 2: bf16 MFMA GEMM, direct-global A-frags + register prefetch; B double-kt
// staged in LDS (16 barriers); fused relu + Wout-dot + pool atomic ----
__global__ __launch_bounds__(256, 2) void k_layer2(const u16* __restrict__ mean1b, const u16* __restrict__ h1b,
                                                   const u16* __restrict__ wcat, const float* __restrict__ b2,
                                                   const int* __restrict__ batch, const float* __restrict__ Wout,
                                                   float* __restrict__ outsum) {
    __shared__ u16 Bs[2][256][40];
    int tid = threadIdx.x;
    int wave = tid >> 6, lane = tid & 63;
    int quad = lane >> 4, m16 = lane & 15;
    int bm = blockIdx.x;
    const size_t r0 = (size_t)(bm * 128 + wave * 32 + m16) * HID + quad * 8;
    const size_t r1 = r0 + 16 * HID;
    f32x4 acc[2][16] = {};
    uint4 a0 = *(const uint4*)(mean1b + r0);
    uint4 a1 = *(const uint4*)(mean1b + r1);
    for (int kt2 = 0; kt2 < 8; kt2++) {
        __syncthreads();
#pragma unroll
        for (int h = 0; h < 2; h++) {
            int kt = kt2 * 2 + h;
#pragma unroll
            for (int i = 0; i < 4; i++) {
                int cidx = tid + 256 * i;
                int n = cidx >> 2, kc = cidx & 3;
                uint4 v = *(const uint4*)(wcat + (size_t)n * 512 + kt * 32 + kc * 8);
                *(uint4*)&Bs[h][n][kc * 8] = v;
            }
        }
        __syncthreads();
#pragma unroll
        for (int h = 0; h < 2; h++) {
            int kt = kt2 * 2 + h;
            uint4 cur0 = a0, cur1 = a1;
            if (kt < 15) {
                int kg = (kt + 1) * 32;
                const u16* An = (kg < 256) ? (mean1b + kg) : (h1b + (kg - 256));
                a0 = *(const uint4*)(An + r0);
                a1 = *(const uint4*)(An + r1);
            }
            bf16x8 af0 = __builtin_bit_cast(bf16x8, cur0);
            bf16x8 af1 = __builtin_bit_cast(bf16x8, cur1);
#pragma unroll
            for (int u = 0; u < 16; u++) {
                bf16x8 bfrag = *(const bf16x8*)&Bs[h][u * 16 + m16][quad * 8];
                acc[0][u] = __builtin_amdgcn_mfma_f32_16x16x32_bf16(af0, bfrag, acc[0][u], 0, 0, 0);
                acc[1][u] = __builtin_amdgcn_mfma_f32_16x16x32_bf16(af1, bfrag, acc[1][u], 0, 0, 0);
            }
        }
    }
    float wo[16], bb[16];
#pragma unroll
    for (int u = 0; u < 16; u++) { int col = u * 16 + m16; wo[u] = Wout[col]; bb[u] = b2[col]; }
#pragma unroll
    for (int t = 0; t < 2; t++) {
#pragma unroll
        for (int i = 0; i < 4; i++) {
            float p = 0.f;
#pragma unroll
            for (int u = 0; u < 16; u++)
                p = fmaf(fmaxf(acc[t][u][i] + bb[u], 0.f), wo[u], p);
#pragma unroll
            for (int off = 8; off > 0; off >>= 1) p += __shfl_down(p, off, 16);
            int row = bm * 128 + wave * 32 + t * 16 + quad * 4 + i;
            if (m16 == 0 && row < N_N) atomicAdd(&outsum[batch[row]], p);
        }
    }
}

// ---- output head ----
__global__ __launch_bounds__(256) void k_out(const float* __restrict__ outsum, const float* __restrict__ gcnt,
                                             const float* __restrict__ bout, float* __restrict__ out) {
    int g = blockIdx.x * 256 + threadIdx.x;
    if (g < N_G) out[g] = outsum[g] / fmaxf(gcnt[g], 1.f) + bout[0];
}

extern "C" void kernel_launch(void* const* d_in, const int* in_sizes, int n_in,
                              void* d_out, int out_size, void* d_ws, size_t ws_size,
                              hipStream_t stream) {
    const float* x    = (const float*)d_in[0];
    const float* pos  = (const float*)d_in[1];
    const int*   ei   = (const int*)d_in[2];
    const int*   batch= (const int*)d_in[3];
    const float* W1l  = (const float*)d_in[4];
    const float* b1   = (const float*)d_in[5];
    const float* W1r  = (const float*)d_in[6];
    const float* W2l  = (const float*)d_in[7];
    const float* b2   = (const float*)d_in[8];
    const float* W2r  = (const float*)d_in[9];
    const float* Wout = (const float*)d_in[10];
    const float* bout = (const float*)d_in[11];
    float* out = (float*)d_out;
    float* ws  = (float*)d_ws;

    float* gcnt  = ws + OFF_GCNT;
    float* outs  = ws + OFF_OUTS;
    int*   rowp  = (int*)(ws + OFF_ROWP);
    int*   deg   = (int*)(ws + OFF_DEG);
    int*   bcnt  = (int*)(ws + OFF_BCNT);
    int*   tot   = (int*)(ws + OFF_TOT);
    u32*   ebuf  = (u32*)(ws + OFF_EBUF);
    int*   csrc  = (int*)(ws + OFF_CSRC);
    u16*   h1b   = (u16*)(ws + OFF_H1B);
    u16*   mean1b= (u16*)(ws + OFF_MEAN1B);
    u16*   wcat  = (u16*)(ws + OFF_WCAT);
    u16*   xpb   = (u16*)(ws + OFF_XP);

    hipMemsetAsync(d_ws, 0, ZERO_BYTES, stream);
    k_bcnt_prep<<<NBLK + PREP_BLKS, 256, 0, stream>>>(ei, x, pos, batch, W2l, W2r,
                                                      bcnt, xpb, gcnt, wcat);
    k_bscanA<<<NB, 512, 0, stream>>>(bcnt, tot);
    k_bfill <<<NBLK, 512, 0, stream>>>(ei, bcnt, tot, ebuf);
    k_sort  <<<NB, 256, 0, stream>>>(ebuf, tot, csrc, deg, rowp);
    k_layer1<<<N_N / 16, 256, 0, stream>>>(xpb, rowp, deg, csrc, W1l, b1, W1r, h1b);
    k_agg   <<<N_N / 4, 256, 0, stream>>>(h1b, rowp, deg, csrc, mean1b);
    k_layer2<<<(N_N + 127) / 128, 256, 0, stream>>>(mean1b, h1b, wcat, b2, batch, Wout, outs);
    k_out   <<<(N_G + 255) / 256, 256, 0, stream>>>(outs, gcnt, bout, out);
}